// Round 1
// baseline (99.224 us; speedup 1.0000x reference)
//
#include <hip/hip_runtime.h>
#include <hip/hip_bf16.h>

#define ORDER 30

// One thread per (b,n) pair: loads float2 (both features), computes the
// Chebyshev recurrence T_n = 2*x*T_{n-1} - T_{n-2} for both scalars in
// registers, writes 60 contiguous floats as 15 float4 stores.
// Output layout: out[p*60 + d*30 + n] = T_n(x[p*2 + d]).
__global__ void __launch_bounds__(256) cheb_encoder_kernel(
    const float* __restrict__ x, float* __restrict__ out, int npairs) {
    int p = blockIdx.x * blockDim.x + threadIdx.x;
    if (p >= npairs) return;

    const float2 xv = reinterpret_cast<const float2*>(x)[p];

    float vals[2 * ORDER];
#pragma unroll
    for (int d = 0; d < 2; ++d) {
        const float xx = d ? xv.y : xv.x;
        float tm1 = 1.0f;
        float t   = xx;
        vals[d * ORDER + 0] = 1.0f;
        vals[d * ORDER + 1] = xx;
#pragma unroll
        for (int n = 2; n < ORDER; ++n) {
            float tn = 2.0f * xx * t - tm1;
            vals[d * ORDER + n] = tn;
            tm1 = t;
            t = tn;
        }
    }

    float4* o = reinterpret_cast<float4*>(out + (size_t)p * (2 * ORDER));
#pragma unroll
    for (int i = 0; i < (2 * ORDER) / 4; ++i) {
        o[i] = make_float4(vals[4 * i + 0], vals[4 * i + 1],
                           vals[4 * i + 2], vals[4 * i + 3]);
    }
}

extern "C" void kernel_launch(void* const* d_in, const int* in_sizes, int n_in,
                              void* d_out, int out_size, void* d_ws, size_t ws_size,
                              hipStream_t stream) {
    const float* x = (const float*)d_in[0];
    float* out = (float*)d_out;
    const int npairs = in_sizes[0] / 2;  // 16*65536 = 1,048,576 (b,n) pairs

    const int block = 256;
    const int grid = (npairs + block - 1) / block;  // 4096 blocks
    cheb_encoder_kernel<<<grid, block, 0, stream>>>(x, out, npairs);
}

// Round 2
// 43.462 us; speedup vs baseline: 2.2830x; 2.2830x over previous
//
#include <hip/hip_runtime.h>
#include <hip/hip_bf16.h>

#define ORDER 30
#define TPB 128   // threads per block == pairs per block
#define PAD 61    // LDS row stride in floats (61 coprime with 32 banks)

// Phase 1: one thread per (b,n) pair computes T_0..T_29 for both features,
//          writes the 60 floats to its padded LDS row.
// Phase 2: block cooperatively streams LDS -> global with perfectly
//          coalesced float4 stores (consecutive lanes -> consecutive 16B).
// Output layout: out[p*60 + d*30 + n] = T_n(x[p*2 + d]).
__global__ void __launch_bounds__(TPB) cheb_encoder_kernel(
    const float* __restrict__ x, float* __restrict__ out, int npairs) {
    __shared__ float lds[TPB * PAD];
    const int tid = threadIdx.x;
    const int pair0 = blockIdx.x * TPB;
    const int p = pair0 + tid;

    if (p < npairs) {
        const float2 xv = reinterpret_cast<const float2*>(x)[p];
        float* row = &lds[tid * PAD];
#pragma unroll
        for (int d = 0; d < 2; ++d) {
            const float xx = d ? xv.y : xv.x;
            const float x2 = 2.0f * xx;
            float tm1 = 1.0f;
            float t   = xx;
            row[d * ORDER + 0] = 1.0f;
            row[d * ORDER + 1] = xx;
#pragma unroll
            for (int n = 2; n < ORDER; ++n) {
                float tn = x2 * t - tm1;
                row[d * ORDER + n] = tn;
                tm1 = t;
                t = tn;
            }
        }
    }
    __syncthreads();

    // Block output region: TPB pairs * 60 floats = TPB*15 float4 quads.
    float4* o4 = reinterpret_cast<float4*>(out) + (size_t)pair0 * 15;
    const int pairs_here = min(npairs - pair0, TPB);
    const int nquads = pairs_here * 15;
#pragma unroll
    for (int i = 0; i < 15; ++i) {
        const int q = i * TPB + tid;   // quad index within block region
        if (q < nquads) {
            const int pl = q / 15;               // local pair
            const int k  = (q - pl * 15) * 4;    // float offset within pair
            const float* r = &lds[pl * PAD + k];
            o4[q] = make_float4(r[0], r[1], r[2], r[3]);
        }
    }
}

extern "C" void kernel_launch(void* const* d_in, const int* in_sizes, int n_in,
                              void* d_out, int out_size, void* d_ws, size_t ws_size,
                              hipStream_t stream) {
    const float* x = (const float*)d_in[0];
    float* out = (float*)d_out;
    const int npairs = in_sizes[0] / 2;  // 16*65536 = 1,048,576 (b,n) pairs

    const int grid = (npairs + TPB - 1) / TPB;  // 8192 blocks
    cheb_encoder_kernel<<<grid, TPB, 0, stream>>>(x, out, npairs);
}